// Round 7
// baseline (307.780 us; speedup 1.0000x reference)
//
#include <hip/hip_runtime.h>

// FFCoSTA: 15-step thermal recurrence (pbm + tiny MLP) over B=65536 elements,
// output = (32,B,13) x2 where slices 0..30 are broadcast copies of the input.
//
// R1:  h[64] un-chunked -> VGPR=256 + spill, 4.8 GB scratch, 4.25 ms.
// R5:  CHUNK=8 rolled, weights in LDS -> 160 us. LDS-port delivery bound.
// R6:  weights->SGPR, runtime-indexed h[64] -> scratch (rule #20), 3.4 ms.
// R7:  R6 fixed -> 260 us: s_load->fma chains serialize at 1 wave/SIMD.
// R8:  MFMA element-per-column, weights in VGPRs, copy folded -> ~95 us
//      (dur = dispatch + ~193+-6; kernel below the 131-us harness fill).
// R9:  de-folded copy (dense store trains) -> ~105 us. R10: address-linear
//      fill-shaped copy -> ~111 us. ALL variants drain writes at ~2.2 TB/s
//      while fillBufferAligned hits 6.6 TB/s on the same buffer. Issue
//      density: falsified. Address order: falsified.
// R11 (this): the one never-varied variable is the STORE OPCODE. All our
//      copies used __builtin_nontemporal_store (L2 no-allocate path); fill
//      uses plain stores (write-allocate, full-line, no RFO since a wave
//      store is 1 KB contiguous; L2->HBM write-back drains at full width).
//      Single change vs R10: nt stores -> plain stores in the copy role.
//      Everything else byte-identical. Floor: 218 MB wr + ~30 MB rd ~ 38 us.

#define STATE 13
#define HID   64
#define PRED  32
#define NSTEP 15

typedef float    f32x4 __attribute__((ext_vector_type(4)));
typedef short    s16x8 __attribute__((ext_vector_type(8)));
typedef unsigned u32x2 __attribute__((ext_vector_type(2)));
typedef float    vfloat4 __attribute__((ext_vector_type(4)));

constexpr int B      = 65536;
constexpr int B13    = B * STATE;     // 851968 floats per slice
constexpr int B13_4  = B13 / 4;       // 212992 float4s per slice
constexpr int CHUNK4 = 8192;          // float4s per copy block (128 KB)
constexpr int CH_PER_S = B13_4 / CHUNK4;   // 26 chunks per slice (exact)
constexpr int CPT    = (PRED - 1) * CH_PER_S;  // 806 copy blocks per tensor
constexpr int NCOPY  = 2 * CPT;       // 1612 copy blocks
constexpr int CBLK   = B / 64;        // 1024 compute blocks, 64 elems each

// ws byte offsets (fragment tables, 15360 B total)
constexpr int WS_W1F = 0;        // [4 tiles][64 lanes] s16x8  = 4096 B
constexpr int WS_W2F = 4096;     // [2 slices][64]      s16x8  = 2048 B
constexpr int WS_B1C = 6144;     // [4][64]             f32x4  = 4096 B
constexpr int WS_B2C = 10240;    // [64]                f32x4  = 1024 B
constexpr int WS_SK  = 11264;    // [4][64]             f32x4  = 4096 B

__device__ __forceinline__ unsigned short f2bf(float f) {
    return __builtin_bit_cast(unsigned short, (__bf16)f);
}
__device__ __forceinline__ unsigned pkbf(float lo, float hi) {
    return (unsigned)f2bf(lo) | ((unsigned)f2bf(hi) << 16);
}
__device__ __forceinline__ float bflo(unsigned u) { return __builtin_bit_cast(float, u << 16); }
__device__ __forceinline__ float bfhi(unsigned u) { return __builtin_bit_cast(float, u & 0xffff0000u); }

// x-dim layout (32): [0..12]=Tr, [13..15]=0 pad, [16..28]=Tw, [29..31]=To,d,t.
// W1 orig rows: 0-12 Tr, 13-25 Tw, 26-28 extras -> orig = nd<13 ? nd : nd-3.
__global__ __launch_bounds__(256) void ffcosta_prep(
    const float* __restrict__ W1, const float* __restrict__ b1,
    const float* __restrict__ W2, const float* __restrict__ b2,
    const float* __restrict__ k_rw, const float* __restrict__ k_ro,
    const float* __restrict__ k_wr, const float* __restrict__ k_wo,
    char* __restrict__ ws)
{
    const int tid = threadIdx.x;
    const float s = 60.0f / 3600.0f;

    // W1T A-frags: A[m=j][k=nd], lane: m=16t+(l&15), k=8*(l>>4)+r
    unsigned short* w1f = (unsigned short*)(ws + WS_W1F);
    for (int idx = tid; idx < 4*64*8; idx += 256) {
        const int t = idx >> 9, l = (idx >> 3) & 63, r = idx & 7;
        const int nd = 8*(l>>4) + r;
        const int j  = 16*t + (l & 15);
        float v = 0.0f;
        if (nd < 13)       v = W1[nd*HID + j];
        else if (nd >= 16) v = W1[(nd-3)*HID + j];
        w1f[idx] = f2bf(v);
    }
    // W2T A-frags: A[m=c][k=j], lane: c=l&15, j=32s+8*(l>>4)+r
    unsigned short* w2f = (unsigned short*)(ws + WS_W2F);
    for (int idx = tid; idx < 2*64*8; idx += 256) {
        const int sl = idx >> 9, l = (idx >> 3) & 63, r = idx & 7;
        const int j = 32*sl + 8*(l>>4) + r;
        const int c = l & 15;
        w2f[idx] = (c < STATE) ? f2bf(W2[j*STATE + c]) : (unsigned short)0;
    }
    // b1 C-frags: C row = m = 16t + 4*(l>>4) + r
    float* b1c = (float*)(ws + WS_B1C);
    for (int idx = tid; idx < 4*64*4; idx += 256) {
        const int t = idx >> 8, l = (idx >> 2) & 63, r = idx & 3;
        b1c[idx] = b1[16*t + 4*(l>>4) + r];
    }
    // b2 C-frag: row = c = 4*(l>>4) + r, pad rows 13-15 = 0
    float* b2c = (float*)(ws + WS_B2C);
    for (int idx = tid; idx < 64*4; idx += 256) {
        const int l = idx >> 2, r = idx & 3;
        const int c = 4*(l>>4) + r;
        b2c[idx] = (c < STATE) ? b2[c] : 0.0f;
    }
    // s*k per lane (state dim = 4*(l>>4)+r), pad dims -> 0 (pbm no-op on pads)
    float* sk = (float*)(ws + WS_SK);
    for (int idx = tid; idx < 4*64*4; idx += 256) {
        const int a = idx >> 8, l = (idx >> 2) & 63, r = idx & 3;
        const int c = 4*(l>>4) + r;
        const float* ka = (a==0)? k_rw : (a==1)? k_ro : (a==2)? k_wr : k_wo;
        sk[idx] = (c < STATE) ? s * ka[c] : 0.0f;
    }
}

__global__ __launch_bounds__(256) void ffcosta_kernel(
    const float* __restrict__ T_room, const float* __restrict__ T_wall,
    const float* __restrict__ T_out,  const float* __restrict__ door,
    const float* __restrict__ timing,
    const char*  __restrict__ ws,
    float* __restrict__ out)
{
    // per-wave-private LDS tiles (no barriers anywhere):
    // +0:    x_hi  16 rows x 64 B   (bf16, x-dim byte = 2*nd)
    // +1024: x_lo
    // +2048: h_hi  16 rows x 128 B  (bf16, byte = 2*j)
    // +4096: h_lo      -> 6144 B per wave, 24576 per block
    __shared__ __align__(16) char smem[4 * 6144];

    float* out0 = out;                              // T_room_new
    float* out1 = out + (size_t)PRED * B13;         // T_wall_new

    if (blockIdx.x < NCOPY) {
        // ------------- copy role: address-linear, PLAIN stores -----------
        // Block owns contiguous 128 KB of output; wave store = 1 KB
        // contiguous (full 64B lines -> write-allocate, no RFO).
        const int  r  = blockIdx.x;
        const bool t1 = (r >= CPT);
        const int  rr = t1 ? (r - CPT) : r;
        const int  sc = rr % CH_PER_S;               // chunk index in slice
        const float* srcp = t1 ? T_wall : T_room;
        const vfloat4* s4 = (const vfloat4*)srcp + sc * CHUNK4 + threadIdx.x;
        vfloat4* d4 = (vfloat4*)(t1 ? out1 : out0) + rr * CHUNK4 + threadIdx.x;
        #pragma unroll 4
        for (int it = 0; it < CHUNK4 / 256; ++it) {  // 32 iters, 4 KB stride
            *d4 = *s4;                               // PLAIN store (the A/B)
            s4 += 256;
            d4 += 256;
        }
        return;
    }

    // ---------------- compute role (R8 engine, math unchanged) ----------
    const int tid  = threadIdx.x;
    const int lane = tid & 63, w = tid >> 6;
    const int el   = lane & 15, hi = lane >> 4;
    const int e    = (blockIdx.x - NCOPY) * 64 + w * 16 + el;

    // ---- invariant per-lane preloads (weights live in VGPRs) ----
    s16x8 w1a[4], w2a[2];
    f32x4 b1c[4], b2c, skrw, skro, skwr, skwo;
    #pragma unroll
    for (int t = 0; t < 4; ++t) {
        w1a[t] = *(const s16x8*)(ws + WS_W1F + (t*64 + lane)*16);
        b1c[t] = *(const f32x4*)(ws + WS_B1C + (t*64 + lane)*16);
    }
    #pragma unroll
    for (int sl = 0; sl < 2; ++sl)
        w2a[sl] = *(const s16x8*)(ws + WS_W2F + (sl*64 + lane)*16);
    b2c  = *(const f32x4*)(ws + WS_B2C + lane*16);
    skrw = *(const f32x4*)(ws + WS_SK +        lane*16);
    skro = *(const f32x4*)(ws + WS_SK + 1024 + lane*16);
    skwr = *(const f32x4*)(ws + WS_SK + 2048 + lane*16);
    skwo = *(const f32x4*)(ws + WS_SK + 3072 + lane*16);

    // ---- state init: lane holds state dims 4*hi + r for element e ----
    // hi==3 lanes: Tr[0]=Tr[12], Tw[0]=Tw[12], Tw[1..3]=To,d,t (x dims 29-31);
    // their sk pads are 0 so pbm passes them through untouched.
    const int off4 = (hi < 3) ? 4*hi : 9;   // hi=3 loads dims 9..12, uses .w
    f32x4 vr, vw;
    __builtin_memcpy(&vr, T_room + e*STATE + off4, 16);
    __builtin_memcpy(&vw, T_wall + e*STATE + off4, 16);
    const float To = T_out [e*PRED + (PRED-1)];
    const float dv = door  [e*PRED + (PRED-1)];
    const float tv = timing[e*PRED + (PRED-1)];
    float Tr[4], Tw[4];
    if (hi < 3) {
        Tr[0]=vr[0]; Tr[1]=vr[1]; Tr[2]=vr[2]; Tr[3]=vr[3];
        Tw[0]=vw[0]; Tw[1]=vw[1]; Tw[2]=vw[2]; Tw[3]=vw[3];
    } else {
        Tr[0]=vr[3]; Tr[1]=0.0f; Tr[2]=0.0f; Tr[3]=0.0f;
        Tw[0]=vw[3]; Tw[1]=To;   Tw[2]=dv;   Tw[3]=tv;
    }

    // ---- LDS offsets (XOR-swizzled, step-invariant) ----
    const int wb = w * 6144;
    const int xk = (el & 3) << 4;          // x-tile row = 64 B
    const int hk = (el & 7) << 4;          // h-tile row = 128 B
    const int a_xw_tr = wb + el*64 + (( 8*hi) ^ xk);   // Tr dims -> bytes 8hi+2r
    const int a_xw_tw = wb + el*64 + ((32 + 8*hi) ^ xk);
    const int a_xr    = wb + el*64 + ((16*hi) ^ xk);   // k = 8hi..8hi+7
    int a_hw[4], a_hr[2];
    #pragma unroll
    for (int t = 0; t < 4; ++t) a_hw[t] = wb + 2048 + el*128 + ((32*t + 8*hi) ^ hk);
    #pragma unroll
    for (int sl = 0; sl < 2; ++sl) a_hr[sl] = wb + 2048 + el*128 + ((64*sl + 16*hi) ^ hk);

    const float s001 = (60.0f/3600.0f) * 0.01f;

    #pragma unroll 1
    for (int n = 0; n < NSTEP; ++n) {
        // pbm, exact fp32 in registers (pad rows: sk=0 -> identity)
        #pragma unroll
        for (int r = 0; r < 4; ++r) {
            const float dA = Tw[r] - Tr[r];
            const float dB = To    - Tr[r];
            const float dC = To    - Tw[r];
            Tr[r] = fmaf(dB, skro[r], fmaf(dA, skrw[r], Tr[r]));
            Tw[r] = fmaf(dC, skwo[r], fmaf(-dA, skwr[r], Tw[r]));
        }

        // pack x_hi + residual x_lo, write (2+2 b64)
        const unsigned tr01 = pkbf(Tr[0], Tr[1]), tr23 = pkbf(Tr[2], Tr[3]);
        const unsigned tw01 = pkbf(Tw[0], Tw[1]), tw23 = pkbf(Tw[2], Tw[3]);
        u32x2 v;
        v[0]=tr01; v[1]=tr23; *(u32x2*)(smem + a_xw_tr) = v;
        v[0]=tw01; v[1]=tw23; *(u32x2*)(smem + a_xw_tw) = v;
        v[0]=pkbf(Tr[0]-bflo(tr01), Tr[1]-bfhi(tr01));
        v[1]=pkbf(Tr[2]-bflo(tr23), Tr[3]-bfhi(tr23));
        *(u32x2*)(smem + a_xw_tr + 1024) = v;
        v[0]=pkbf(Tw[0]-bflo(tw01), Tw[1]-bfhi(tw01));
        v[1]=pkbf(Tw[2]-bflo(tw23), Tw[3]-bfhi(tw23));
        *(u32x2*)(smem + a_xw_tw + 1024) = v;

        // B-frags for layer 1 (same-wave lgkmcnt ordering, no barrier)
        const s16x8 xbh = *(const s16x8*)(smem + a_xr);
        const s16x8 xbl = *(const s16x8*)(smem + a_xr + 1024);

        // layer 1: hT[j][e] = b1 + W1T@x_hi + W1T@x_lo
        f32x4 acc[4];
        #pragma unroll
        for (int t = 0; t < 4; ++t) {
            acc[t] = __builtin_amdgcn_mfma_f32_16x16x32_bf16(w1a[t], xbh, b1c[t], 0, 0, 0);
            acc[t] = __builtin_amdgcn_mfma_f32_16x16x32_bf16(w1a[t], xbl, acc[t], 0, 0, 0);
        }

        // relu, pack h_hi + h_lo, write (4+4 b64)
        #pragma unroll
        for (int t = 0; t < 4; ++t) {
            const float h0 = fmaxf(acc[t][0], 0.0f), h1 = fmaxf(acc[t][1], 0.0f);
            const float h2 = fmaxf(acc[t][2], 0.0f), h3 = fmaxf(acc[t][3], 0.0f);
            const unsigned p01 = pkbf(h0, h1), p23 = pkbf(h2, h3);
            u32x2 hv; hv[0]=p01; hv[1]=p23;
            *(u32x2*)(smem + a_hw[t]) = hv;
            hv[0] = pkbf(h0-bflo(p01), h1-bfhi(p01));
            hv[1] = pkbf(h2-bflo(p23), h3-bfhi(p23));
            *(u32x2*)(smem + a_hw[t] + 2048) = hv;
        }

        const s16x8 hb0 = *(const s16x8*)(smem + a_hr[0]);
        const s16x8 hb1 = *(const s16x8*)(smem + a_hr[1]);
        const s16x8 hl0 = *(const s16x8*)(smem + a_hr[0] + 2048);
        const s16x8 hl1 = *(const s16x8*)(smem + a_hr[1] + 2048);

        // layer 2: srcT[c][e] = b2 + W2T@h_hi + W2T@h_lo  (pad rows -> 0)
        f32x4 sv = b2c;
        sv = __builtin_amdgcn_mfma_f32_16x16x32_bf16(w2a[0], hb0, sv, 0, 0, 0);
        sv = __builtin_amdgcn_mfma_f32_16x16x32_bf16(w2a[1], hb1, sv, 0, 0, 0);
        sv = __builtin_amdgcn_mfma_f32_16x16x32_bf16(w2a[0], hl0, sv, 0, 0, 0);
        sv = __builtin_amdgcn_mfma_f32_16x16x32_bf16(w2a[1], hl1, sv, 0, 0, 0);

        // state update: Tr += s*0.01*src_raw (pad rows get +0)
        #pragma unroll
        for (int r = 0; r < 4; ++r) Tr[r] = fmaf(sv[r], s001, Tr[r]);
    }

    // final slice 31: lane stores dims 4hi..4hi+3 (hi=3: dim 12 only)
    float* p0 = out0 + (size_t)(PRED-1) * B13 + e*STATE;
    float* p1 = p0 + (size_t)PRED * B13;
    if (hi < 3) {
        f32x4 s0, s1;
        s0[0]=Tr[0]; s0[1]=Tr[1]; s0[2]=Tr[2]; s0[3]=Tr[3];
        s1[0]=Tw[0]; s1[1]=Tw[1]; s1[2]=Tw[2]; s1[3]=Tw[3];
        __builtin_memcpy(p0 + 4*hi, &s0, 16);
        __builtin_memcpy(p1 + 4*hi, &s1, 16);
    } else {
        p0[12] = Tr[0];
        p1[12] = Tw[0];
    }
}

extern "C" void kernel_launch(void* const* d_in, const int* in_sizes, int n_in,
                              void* d_out, int out_size, void* d_ws, size_t ws_size,
                              hipStream_t stream) {
    const float* T_room = (const float*)d_in[0];
    const float* T_wall = (const float*)d_in[1];
    const float* T_out  = (const float*)d_in[2];
    const float* door   = (const float*)d_in[3];
    const float* timing = (const float*)d_in[4];
    const float* k_rw   = (const float*)d_in[5];
    const float* k_ro   = (const float*)d_in[6];
    const float* k_wr   = (const float*)d_in[7];
    const float* k_wo   = (const float*)d_in[8];
    const float* W1     = (const float*)d_in[9];
    const float* b1     = (const float*)d_in[10];
    const float* W2     = (const float*)d_in[11];
    const float* b2     = (const float*)d_in[12];
    float* out = (float*)d_out;
    char*  ws  = (char*)d_ws;

    ffcosta_prep<<<1, 256, 0, stream>>>(W1, b1, W2, b2, k_rw, k_ro, k_wr, k_wo, ws);
    ffcosta_kernel<<<NCOPY + CBLK, 256, 0, stream>>>(
        T_room, T_wall, T_out, door, timing, ws, out);
}

// Round 8
// 288.251 us; speedup vs baseline: 1.0677x; 1.0677x over previous
//
#include <hip/hip_runtime.h>

// FFCoSTA: 15-step thermal recurrence (pbm + tiny MLP) over B=65536 elements,
// output = (32,B,13) x2 where slices 0..30 are broadcast copies of the input.
//
// R1:  h[64] un-chunked -> VGPR=256 + spill, 4.8 GB scratch, 4.25 ms.
// R5:  weights in LDS -> 160 us (LDS-port delivery bound, 1 wave/SIMD).
// R6/R7: weights via s_load -> 260 us (scalar-chain latency, no TLP).
// R8:  MFMA element-per-column, weights in VGPRs, copy folded -> ~89 us.
// R9-R11: copy-role ablation, all ~102-115 us at ~2.2 TB/s write drain:
//      issue density (R9), address order (R10), store opcode nt->plain (R11)
//      ALL FALSIFIED. Note: harness fill WRITE_SIZE = 4x out buffer -> fill
//      resets the WORKSPACE; 6.5 TB/s is device capability, not out-specific.
// R12 (this): the never-varied variable is GRID SHAPE / frontier coherence.
//      fill: ~256 blocks (~1/CU), waves run long dense store trains, chip
//      frontier = one ~1 MB window sweeping linearly. Ours: 832-1612 static
//      blocks all resident -> thousands of drifting streams scattered over
//      218 MB -> HBM row thrash at ~2.2 TB/s (consistent with R8-R11).
//      Copy role rebuilt as fill-clone: 208 blocks (B13_4 = 4*53248), thread
//      owns 4 q-positions, loads 8 source float4s ONCE to regs, then 31 x 8
//      back-to-back plain stores (store-only steady state, dense trains).
//      Frontier = one moving 6.8 MB slice-pair window. Copy dispatched
//      first; compute role (R8 engine, byte-identical) backfills.
//      Floor: 218 MB wr + ~20 MB rd ~ 38 us.

#define STATE 13
#define HID   64
#define PRED  32
#define NSTEP 15

typedef float    f32x4 __attribute__((ext_vector_type(4)));
typedef short    s16x8 __attribute__((ext_vector_type(8)));
typedef unsigned u32x2 __attribute__((ext_vector_type(2)));
typedef float    vfloat4 __attribute__((ext_vector_type(4)));

constexpr int B      = 65536;
constexpr int B13    = B * STATE;     // 851968 floats per slice
constexpr int B13_4  = B13 / 4;       // 212992 float4s per slice
constexpr int QT     = B13_4 / 4;     // 53248: q-positions per k-group
constexpr int NCPB   = QT / 256;      // 208 copy blocks (~0.8/CU, fill-like)
constexpr int CBLK   = B / 64;        // 1024 compute blocks, 64 elems each

// ws byte offsets (fragment tables, 15360 B total)
constexpr int WS_W1F = 0;        // [4 tiles][64 lanes] s16x8  = 4096 B
constexpr int WS_W2F = 4096;     // [2 slices][64]      s16x8  = 2048 B
constexpr int WS_B1C = 6144;     // [4][64]             f32x4  = 4096 B
constexpr int WS_B2C = 10240;    // [64]                f32x4  = 1024 B
constexpr int WS_SK  = 11264;    // [4][64]             f32x4  = 4096 B

__device__ __forceinline__ unsigned short f2bf(float f) {
    return __builtin_bit_cast(unsigned short, (__bf16)f);
}
__device__ __forceinline__ unsigned pkbf(float lo, float hi) {
    return (unsigned)f2bf(lo) | ((unsigned)f2bf(hi) << 16);
}
__device__ __forceinline__ float bflo(unsigned u) { return __builtin_bit_cast(float, u << 16); }
__device__ __forceinline__ float bfhi(unsigned u) { return __builtin_bit_cast(float, u & 0xffff0000u); }

// x-dim layout (32): [0..12]=Tr, [13..15]=0 pad, [16..28]=Tw, [29..31]=To,d,t.
// W1 orig rows: 0-12 Tr, 13-25 Tw, 26-28 extras -> orig = nd<13 ? nd : nd-3.
__global__ __launch_bounds__(256) void ffcosta_prep(
    const float* __restrict__ W1, const float* __restrict__ b1,
    const float* __restrict__ W2, const float* __restrict__ b2,
    const float* __restrict__ k_rw, const float* __restrict__ k_ro,
    const float* __restrict__ k_wr, const float* __restrict__ k_wo,
    char* __restrict__ ws)
{
    const int tid = threadIdx.x;
    const float s = 60.0f / 3600.0f;

    // W1T A-frags: A[m=j][k=nd], lane: m=16t+(l&15), k=8*(l>>4)+r
    unsigned short* w1f = (unsigned short*)(ws + WS_W1F);
    for (int idx = tid; idx < 4*64*8; idx += 256) {
        const int t = idx >> 9, l = (idx >> 3) & 63, r = idx & 7;
        const int nd = 8*(l>>4) + r;
        const int j  = 16*t + (l & 15);
        float v = 0.0f;
        if (nd < 13)       v = W1[nd*HID + j];
        else if (nd >= 16) v = W1[(nd-3)*HID + j];
        w1f[idx] = f2bf(v);
    }
    // W2T A-frags: A[m=c][k=j], lane: c=l&15, j=32s+8*(l>>4)+r
    unsigned short* w2f = (unsigned short*)(ws + WS_W2F);
    for (int idx = tid; idx < 2*64*8; idx += 256) {
        const int sl = idx >> 9, l = (idx >> 3) & 63, r = idx & 7;
        const int j = 32*sl + 8*(l>>4) + r;
        const int c = l & 15;
        w2f[idx] = (c < STATE) ? f2bf(W2[j*STATE + c]) : (unsigned short)0;
    }
    // b1 C-frags: C row = m = 16t + 4*(l>>4) + r
    float* b1c = (float*)(ws + WS_B1C);
    for (int idx = tid; idx < 4*64*4; idx += 256) {
        const int t = idx >> 8, l = (idx >> 2) & 63, r = idx & 3;
        b1c[idx] = b1[16*t + 4*(l>>4) + r];
    }
    // b2 C-frag: row = c = 4*(l>>4) + r, pad rows 13-15 = 0
    float* b2c = (float*)(ws + WS_B2C);
    for (int idx = tid; idx < 64*4; idx += 256) {
        const int l = idx >> 2, r = idx & 3;
        const int c = 4*(l>>4) + r;
        b2c[idx] = (c < STATE) ? b2[c] : 0.0f;
    }
    // s*k per lane (state dim = 4*(l>>4)+r), pad dims -> 0 (pbm no-op on pads)
    float* sk = (float*)(ws + WS_SK);
    for (int idx = tid; idx < 4*64*4; idx += 256) {
        const int a = idx >> 8, l = (idx >> 2) & 63, r = idx & 3;
        const int c = 4*(l>>4) + r;
        const float* ka = (a==0)? k_rw : (a==1)? k_ro : (a==2)? k_wr : k_wo;
        sk[idx] = (c < STATE) ? s * ka[c] : 0.0f;
    }
}

__global__ __launch_bounds__(256) void ffcosta_kernel(
    const float* __restrict__ T_room, const float* __restrict__ T_wall,
    const float* __restrict__ T_out,  const float* __restrict__ door,
    const float* __restrict__ timing,
    const char*  __restrict__ ws,
    float* __restrict__ out)
{
    // per-wave-private LDS tiles (no barriers anywhere):
    // +0:    x_hi  16 rows x 64 B   (bf16, x-dim byte = 2*nd)
    // +1024: x_lo
    // +2048: h_hi  16 rows x 128 B  (bf16, byte = 2*j)
    // +4096: h_lo      -> 6144 B per wave, 24576 per block
    __shared__ __align__(16) char smem[4 * 6144];

    float* out0 = out;                              // T_room_new
    float* out1 = out + (size_t)PRED * B13;         // T_wall_new

    if (blockIdx.x < NCPB) {
        // ------------- copy role: fill-clone -----------------------------
        // 208 blocks (~0.8/CU). Thread owns q0 + k*QT (k=0..3): loads its
        // 8 source float4s ONCE, then 31 iterations x 8 dense plain stores.
        // All copy waves advance through slice p together -> chip write
        // frontier = one moving 6.8 MB slice-pair window (fill-shaped).
        const int q0 = blockIdx.x * 256 + threadIdx.x;   // [0, QT)
        vfloat4 r[4], w[4];
        #pragma unroll
        for (int k = 0; k < 4; ++k) {
            r[k] = ((const vfloat4*)T_room)[q0 + k*QT];
            w[k] = ((const vfloat4*)T_wall)[q0 + k*QT];
        }
        vfloat4* o0 = (vfloat4*)out0 + q0;
        vfloat4* o1 = (vfloat4*)out1 + q0;
        #pragma unroll 1
        for (int p = 0; p < PRED - 1; ++p) {
            #pragma unroll
            for (int k = 0; k < 4; ++k) o0[k*QT] = r[k];
            #pragma unroll
            for (int k = 0; k < 4; ++k) o1[k*QT] = w[k];
            o0 += B13_4;
            o1 += B13_4;
        }
        return;
    }

    // ---------------- compute role (R8 engine, math unchanged) ----------
    const int tid  = threadIdx.x;
    const int lane = tid & 63, w = tid >> 6;
    const int el   = lane & 15, hi = lane >> 4;
    const int e    = (blockIdx.x - NCPB) * 64 + w * 16 + el;

    // ---- invariant per-lane preloads (weights live in VGPRs) ----
    s16x8 w1a[4], w2a[2];
    f32x4 b1c[4], b2c, skrw, skro, skwr, skwo;
    #pragma unroll
    for (int t = 0; t < 4; ++t) {
        w1a[t] = *(const s16x8*)(ws + WS_W1F + (t*64 + lane)*16);
        b1c[t] = *(const f32x4*)(ws + WS_B1C + (t*64 + lane)*16);
    }
    #pragma unroll
    for (int sl = 0; sl < 2; ++sl)
        w2a[sl] = *(const s16x8*)(ws + WS_W2F + (sl*64 + lane)*16);
    b2c  = *(const f32x4*)(ws + WS_B2C + lane*16);
    skrw = *(const f32x4*)(ws + WS_SK +        lane*16);
    skro = *(const f32x4*)(ws + WS_SK + 1024 + lane*16);
    skwr = *(const f32x4*)(ws + WS_SK + 2048 + lane*16);
    skwo = *(const f32x4*)(ws + WS_SK + 3072 + lane*16);

    // ---- state init: lane holds state dims 4*hi + r for element e ----
    // hi==3 lanes: Tr[0]=Tr[12], Tw[0]=Tw[12], Tw[1..3]=To,d,t (x dims 29-31);
    // their sk pads are 0 so pbm passes them through untouched.
    const int off4 = (hi < 3) ? 4*hi : 9;   // hi=3 loads dims 9..12, uses .w
    f32x4 vr, vw;
    __builtin_memcpy(&vr, T_room + e*STATE + off4, 16);
    __builtin_memcpy(&vw, T_wall + e*STATE + off4, 16);
    const float To = T_out [e*PRED + (PRED-1)];
    const float dv = door  [e*PRED + (PRED-1)];
    const float tv = timing[e*PRED + (PRED-1)];
    float Tr[4], Tw[4];
    if (hi < 3) {
        Tr[0]=vr[0]; Tr[1]=vr[1]; Tr[2]=vr[2]; Tr[3]=vr[3];
        Tw[0]=vw[0]; Tw[1]=vw[1]; Tw[2]=vw[2]; Tw[3]=vw[3];
    } else {
        Tr[0]=vr[3]; Tr[1]=0.0f; Tr[2]=0.0f; Tr[3]=0.0f;
        Tw[0]=vw[3]; Tw[1]=To;   Tw[2]=dv;   Tw[3]=tv;
    }

    // ---- LDS offsets (XOR-swizzled, step-invariant) ----
    const int wb = w * 6144;
    const int xk = (el & 3) << 4;          // x-tile row = 64 B
    const int hk = (el & 7) << 4;          // h-tile row = 128 B
    const int a_xw_tr = wb + el*64 + (( 8*hi) ^ xk);   // Tr dims -> bytes 8hi+2r
    const int a_xw_tw = wb + el*64 + ((32 + 8*hi) ^ xk);
    const int a_xr    = wb + el*64 + ((16*hi) ^ xk);   // k = 8hi..8hi+7
    int a_hw[4], a_hr[2];
    #pragma unroll
    for (int t = 0; t < 4; ++t) a_hw[t] = wb + 2048 + el*128 + ((32*t + 8*hi) ^ hk);
    #pragma unroll
    for (int sl = 0; sl < 2; ++sl) a_hr[sl] = wb + 2048 + el*128 + ((64*sl + 16*hi) ^ hk);

    const float s001 = (60.0f/3600.0f) * 0.01f;

    #pragma unroll 1
    for (int n = 0; n < NSTEP; ++n) {
        // pbm, exact fp32 in registers (pad rows: sk=0 -> identity)
        #pragma unroll
        for (int r = 0; r < 4; ++r) {
            const float dA = Tw[r] - Tr[r];
            const float dB = To    - Tr[r];
            const float dC = To    - Tw[r];
            Tr[r] = fmaf(dB, skro[r], fmaf(dA, skrw[r], Tr[r]));
            Tw[r] = fmaf(dC, skwo[r], fmaf(-dA, skwr[r], Tw[r]));
        }

        // pack x_hi + residual x_lo, write (2+2 b64)
        const unsigned tr01 = pkbf(Tr[0], Tr[1]), tr23 = pkbf(Tr[2], Tr[3]);
        const unsigned tw01 = pkbf(Tw[0], Tw[1]), tw23 = pkbf(Tw[2], Tw[3]);
        u32x2 v;
        v[0]=tr01; v[1]=tr23; *(u32x2*)(smem + a_xw_tr) = v;
        v[0]=tw01; v[1]=tw23; *(u32x2*)(smem + a_xw_tw) = v;
        v[0]=pkbf(Tr[0]-bflo(tr01), Tr[1]-bfhi(tr01));
        v[1]=pkbf(Tr[2]-bflo(tr23), Tr[3]-bfhi(tr23));
        *(u32x2*)(smem + a_xw_tr + 1024) = v;
        v[0]=pkbf(Tw[0]-bflo(tw01), Tw[1]-bfhi(tw01));
        v[1]=pkbf(Tw[2]-bflo(tw23), Tw[3]-bfhi(tw23));
        *(u32x2*)(smem + a_xw_tw + 1024) = v;

        // B-frags for layer 1 (same-wave lgkmcnt ordering, no barrier)
        const s16x8 xbh = *(const s16x8*)(smem + a_xr);
        const s16x8 xbl = *(const s16x8*)(smem + a_xr + 1024);

        // layer 1: hT[j][e] = b1 + W1T@x_hi + W1T@x_lo
        f32x4 acc[4];
        #pragma unroll
        for (int t = 0; t < 4; ++t) {
            acc[t] = __builtin_amdgcn_mfma_f32_16x16x32_bf16(w1a[t], xbh, b1c[t], 0, 0, 0);
            acc[t] = __builtin_amdgcn_mfma_f32_16x16x32_bf16(w1a[t], xbl, acc[t], 0, 0, 0);
        }

        // relu, pack h_hi + h_lo, write (4+4 b64)
        #pragma unroll
        for (int t = 0; t < 4; ++t) {
            const float h0 = fmaxf(acc[t][0], 0.0f), h1 = fmaxf(acc[t][1], 0.0f);
            const float h2 = fmaxf(acc[t][2], 0.0f), h3 = fmaxf(acc[t][3], 0.0f);
            const unsigned p01 = pkbf(h0, h1), p23 = pkbf(h2, h3);
            u32x2 hv; hv[0]=p01; hv[1]=p23;
            *(u32x2*)(smem + a_hw[t]) = hv;
            hv[0] = pkbf(h0-bflo(p01), h1-bfhi(p01));
            hv[1] = pkbf(h2-bflo(p23), h3-bfhi(p23));
            *(u32x2*)(smem + a_hw[t] + 2048) = hv;
        }

        const s16x8 hb0 = *(const s16x8*)(smem + a_hr[0]);
        const s16x8 hb1 = *(const s16x8*)(smem + a_hr[1]);
        const s16x8 hl0 = *(const s16x8*)(smem + a_hr[0] + 2048);
        const s16x8 hl1 = *(const s16x8*)(smem + a_hr[1] + 2048);

        // layer 2: srcT[c][e] = b2 + W2T@h_hi + W2T@h_lo  (pad rows -> 0)
        f32x4 sv = b2c;
        sv = __builtin_amdgcn_mfma_f32_16x16x32_bf16(w2a[0], hb0, sv, 0, 0, 0);
        sv = __builtin_amdgcn_mfma_f32_16x16x32_bf16(w2a[1], hb1, sv, 0, 0, 0);
        sv = __builtin_amdgcn_mfma_f32_16x16x32_bf16(w2a[0], hl0, sv, 0, 0, 0);
        sv = __builtin_amdgcn_mfma_f32_16x16x32_bf16(w2a[1], hl1, sv, 0, 0, 0);

        // state update: Tr += s*0.01*src_raw (pad rows get +0)
        #pragma unroll
        for (int r = 0; r < 4; ++r) Tr[r] = fmaf(sv[r], s001, Tr[r]);
    }

    // final slice 31: lane stores dims 4hi..4hi+3 (hi=3: dim 12 only)
    float* p0 = out0 + (size_t)(PRED-1) * B13 + e*STATE;
    float* p1 = p0 + (size_t)PRED * B13;
    if (hi < 3) {
        f32x4 s0, s1;
        s0[0]=Tr[0]; s0[1]=Tr[1]; s0[2]=Tr[2]; s0[3]=Tr[3];
        s1[0]=Tw[0]; s1[1]=Tw[1]; s1[2]=Tw[2]; s1[3]=Tw[3];
        __builtin_memcpy(p0 + 4*hi, &s0, 16);
        __builtin_memcpy(p1 + 4*hi, &s1, 16);
    } else {
        p0[12] = Tr[0];
        p1[12] = Tw[0];
    }
}

extern "C" void kernel_launch(void* const* d_in, const int* in_sizes, int n_in,
                              void* d_out, int out_size, void* d_ws, size_t ws_size,
                              hipStream_t stream) {
    const float* T_room = (const float*)d_in[0];
    const float* T_wall = (const float*)d_in[1];
    const float* T_out  = (const float*)d_in[2];
    const float* door   = (const float*)d_in[3];
    const float* timing = (const float*)d_in[4];
    const float* k_rw   = (const float*)d_in[5];
    const float* k_ro   = (const float*)d_in[6];
    const float* k_wr   = (const float*)d_in[7];
    const float* k_wo   = (const float*)d_in[8];
    const float* W1     = (const float*)d_in[9];
    const float* b1     = (const float*)d_in[10];
    const float* W2     = (const float*)d_in[11];
    const float* b2     = (const float*)d_in[12];
    float* out = (float*)d_out;
    char*  ws  = (char*)d_ws;

    ffcosta_prep<<<1, 256, 0, stream>>>(W1, b1, W2, b2, k_rw, k_ro, k_wr, k_wo, ws);
    ffcosta_kernel<<<NCPB + CBLK, 256, 0, stream>>>(
        T_room, T_wall, T_out, door, timing, ws, out);
}